// Round 1
// 359.161 us; speedup vs baseline: 1.1162x; 1.1162x over previous
//
#include <hip/hip_runtime.h>
#include <hip/hip_bf16.h>
#include <math.h>

// Problem constants
constexpr int Ncfg = 4096;
constexpr int Dcfg = 4096;
constexpr int Ocfg = 4096;
constexpr int Ecfg = 8;
constexpr int Rcfg = 16;
constexpr int KD   = Dcfg + Ecfg * Rcfg;   // 4224 fused-K
constexpr int NKT  = KD / 64;              // 66 K-tiles of BK=64
constexpr float ALPHA_C = 1.0f;
constexpr double TEMP_C = 1.0;

// Workspace layout (bytes)
constexpr size_t BT_OFF = 0;                                   // B'^T bf16 [O][KD]
constexpr size_t AP_OFF = BT_OFF + (size_t)Ocfg * KD * 2;      // A'   bf16 [N][KD]
constexpr size_t AT_OFF = AP_OFF + (size_t)Ncfg * KD * 2;      // lora_A^T bf16 [E][R][D]
constexpr size_t G_OFF  = AT_OFF + (size_t)Ecfg * Rcfg * Dcfg * 2; // gates f32 [N][16]

typedef short bf16x8 __attribute__((ext_vector_type(8)));
typedef float f32x4  __attribute__((ext_vector_type(4)));

__device__ __forceinline__ void async_load16(const __hip_bfloat16* g, __hip_bfloat16* l) {
  __builtin_amdgcn_global_load_lds((__attribute__((address_space(1))) void*)(g),
                                   (__attribute__((address_space(3))) void*)(l), 16, 0, 0);
}

// ---------------------------------------------------------------------------
// Launch 1: four MUTUALLY INDEPENDENT families in one wide kernel.
//   (unchanged — verified)
// ---------------------------------------------------------------------------
__global__ __launch_bounds__(256) void prep_parallel_kernel(
    const float* __restrict__ x,  const float* __restrict__ gw,
    const float* __restrict__ W,  const float* __restrict__ lB,
    const float* __restrict__ lA,
    float* __restrict__ gates, __hip_bfloat16* __restrict__ Ap,
    __hip_bfloat16* __restrict__ BT, __hip_bfloat16* __restrict__ AT) {
  __shared__ union {
    float tile[64][65];     // 64x64 transpose staging (+1 pad)
    float atile[256][17];   // loraA staging
  } sm;
  const int bid = blockIdx.x;
  const int tid = threadIdx.x;

  if (bid < 512) {
    // ---------------- gates + base-scale ----------------
    const int wave = tid >> 6, lane = tid & 63;
    const int na = bid * 8 + wave * 2, nb = na + 1;   // 2 rows per wave
    const float4* xa4 = (const float4*)(x + (size_t)na * Dcfg);
    const float4* xb4 = (const float4*)(x + (size_t)nb * Dcfg);
    const float4* gw4 = (const float4*)gw;
    double accA[9], accB[9];
#pragma unroll
    for (int e = 0; e < 9; e++) { accA[e] = 0.0; accB[e] = 0.0; }
    for (int i = 0; i < 16; i++) {
      int fi = lane + 64 * i;
      float4 xa = xa4[fi], xb = xb4[fi];
#pragma unroll
      for (int e = 0; e < 9; e++) {
        float4 w = gw4[e * 1024 + fi];   // shared load serves both rows
        accA[e] += (double)xa.x * (double)w.x + (double)xa.y * (double)w.y +
                   (double)xa.z * (double)w.z + (double)xa.w * (double)w.w;
        accB[e] += (double)xb.x * (double)w.x + (double)xb.y * (double)w.y +
                   (double)xb.z * (double)w.z + (double)xb.w * (double)w.w;
      }
    }
#pragma unroll
    for (int off = 32; off >= 1; off >>= 1) {
#pragma unroll
      for (int e = 0; e < 9; e++) {
        accA[e] += __shfl_xor(accA[e], off, 64);
        accB[e] += __shfl_xor(accB[e], off, 64);
      }
    }
    float g0A_l = 0.f, g0B_l = 0.f;
    if (lane == 0) {
#pragma unroll
      for (int r = 0; r < 2; r++) {
        double lg[9];
#pragma unroll
        for (int e = 0; e < 9; e++) lg[e] = r ? accB[e] : accA[e];
        // top-2 over experts 1..8, lowest index wins ties (jax top_k)
        int i1 = 1;
        for (int e = 2; e <= 8; e++) if (lg[e] > lg[i1]) i1 = e;
        int i2 = -1; double v2 = -1e300;
        for (int e = 1; e <= 8; e++) if (e != i1 && lg[e] > v2) { v2 = lg[e]; i2 = e; }
        double vals[9];
        vals[0] = lg[0];
        for (int e = 1; e <= 8; e++) vals[e] = (e == i1 || e == i2) ? lg[e] : 0.0; // zeros, NOT -inf
        double mx = vals[0];
        for (int e = 1; e < 9; e++) mx = fmax(mx, vals[e]);
        double se = 0.0, ex[9];
        for (int e = 0; e < 9; e++) { ex[e] = exp((vals[e] - mx) / TEMP_C); se += ex[e]; }
        const int n = r ? nb : na;
        for (int e = 0; e < 9; e++) gates[n * 16 + e] = (float)(ex[e] / se);
        if (r == 0) g0A_l = (float)(ex[0] / se); else g0B_l = (float)(ex[0] / se);
      }
    }
    const float g0A = __shfl(g0A_l, 0, 64);
    const float g0B = __shfl(g0B_l, 0, 64);
    // Phase B: base-scale writes (x rows are L2-hot from phase A)
    __hip_bfloat16* ara = Ap + (size_t)na * KD;
    __hip_bfloat16* arb = Ap + (size_t)nb * KD;
    for (int i = 0; i < 16; i++) {
      int fi = lane + 64 * i;
      float4 xa = xa4[fi], xb = xb4[fi];
      union { ushort4 u; __hip_bfloat16 h[4]; } p;
      p.h[0] = __float2bfloat16(g0A * xa.x);
      p.h[1] = __float2bfloat16(g0A * xa.y);
      p.h[2] = __float2bfloat16(g0A * xa.z);
      p.h[3] = __float2bfloat16(g0A * xa.w);
      *(ushort4*)(ara + (size_t)fi * 4) = p.u;
      p.h[0] = __float2bfloat16(g0B * xb.x);
      p.h[1] = __float2bfloat16(g0B * xb.y);
      p.h[2] = __float2bfloat16(g0B * xb.z);
      p.h[3] = __float2bfloat16(g0B * xb.w);
      *(ushort4*)(arb + (size_t)fi * 4) = p.u;
    }
  } else if (bid < 4736) {
    // ---------------- W / lora_B transpose+cast, 64x64 tile ----------------
    const float* src; int r0, c0, dstOff;
    if (bid < 4608) {          // W: id in [0,4096)
      int id = bid - 512;
      src = W; r0 = (id & 63) * 64; c0 = (id >> 6) * 64; dstOff = 0;
    } else {                   // lB flat (128 x O): id in [0,128)
      int id = bid - 4608;
      src = lB; r0 = (id & 1) * 64; c0 = (id >> 1) * 64; dstOff = Dcfg;
    }
#pragma unroll
    for (int it = 0; it < 4; it++) {
      int flat = it * 256 + tid;
      int i = flat >> 4, f = flat & 15;
      float4 v = *(const float4*)(src + (size_t)(r0 + i) * Ocfg + c0 + 4 * f);
      sm.tile[i][4 * f + 0] = v.x;
      sm.tile[i][4 * f + 1] = v.y;
      sm.tile[i][4 * f + 2] = v.z;
      sm.tile[i][4 * f + 3] = v.w;
    }
    __syncthreads();
#pragma unroll
    for (int it = 0; it < 4; it++) {
      int flat = it * 256 + tid;
      int j = flat >> 4, q = flat & 15;
      union { ushort4 u; __hip_bfloat16 h[4]; } p;
      p.h[0] = __float2bfloat16(sm.tile[4 * q + 0][j]);
      p.h[1] = __float2bfloat16(sm.tile[4 * q + 1][j]);
      p.h[2] = __float2bfloat16(sm.tile[4 * q + 2][j]);
      p.h[3] = __float2bfloat16(sm.tile[4 * q + 3][j]);
      *(ushort4*)(BT + (size_t)(c0 + j) * KD + dstOff + r0 + 4 * q) = p.u;
    }
  } else {
    // ---------------- lora_A (E,D,R) -> AT (E,R,D) bf16 ----------------
    const int id = bid - 4736;
    const int e = id >> 4, d0 = (id & 15) * 256;
#pragma unroll
    for (int it = 0; it < 16; it++) {
      int idx = it * 256 + tid;
      int d = idx >> 4, rr = idx & 15;
      sm.atile[d][rr] = lA[((size_t)e * Dcfg + d0 + d) * Rcfg + rr];
    }
    __syncthreads();
#pragma unroll
    for (int rr = 0; rr < Rcfg; rr++) {
      AT[((size_t)e * Rcfg + rr) * Dcfg + d0 + tid] = __float2bfloat16(sm.atile[tid][rr]);
    }
  }
}

// ---------------------------------------------------------------------------
// Launch 2: t[n,e,:] = x[n,:] @ lora_A[e] via 16x16x32 bf16 MFMA.
//   (unchanged — verified)
// ---------------------------------------------------------------------------
__global__ __launch_bounds__(512) void lora_t_kernel(
    const float* __restrict__ x, const __hip_bfloat16* __restrict__ AT,
    const float* __restrict__ gates, __hip_bfloat16* __restrict__ Ap) {
  const int n0 = blockIdx.x * 16;
  const int tid = threadIdx.x;
  const int wave = tid >> 6, lane = tid & 63;
  const int m = lane & 15, quad = lane >> 4;
  const int kbase = wave * 512;

  f32x4 acc[8] = {};
  const float* xrow = x + (size_t)(n0 + m) * Dcfg + kbase + quad * 8;
  const __hip_bfloat16* atb = AT + (size_t)m * Dcfg + kbase + quad * 8;
#pragma unroll 2
  for (int kb = 0; kb < 512; kb += 32) {
    float4 x0 = *(const float4*)(xrow + kb);
    float4 x1 = *(const float4*)(xrow + kb + 4);
    union { bf16x8 v; __hip_bfloat16 h[8]; } a;
    a.h[0] = __float2bfloat16(x0.x); a.h[1] = __float2bfloat16(x0.y);
    a.h[2] = __float2bfloat16(x0.z); a.h[3] = __float2bfloat16(x0.w);
    a.h[4] = __float2bfloat16(x1.x); a.h[5] = __float2bfloat16(x1.y);
    a.h[6] = __float2bfloat16(x1.z); a.h[7] = __float2bfloat16(x1.w);
#pragma unroll
    for (int e = 0; e < Ecfg; e++) {
      bf16x8 b = *(const bf16x8*)(atb + (size_t)e * Rcfg * Dcfg + kb);
      acc[e] = __builtin_amdgcn_mfma_f32_16x16x32_bf16(a.v, b, acc[e], 0, 0, 0);
    }
  }
  __shared__ f32x4 red[8][8][64];
#pragma unroll
  for (int e = 0; e < Ecfg; e++) red[wave][e][lane] = acc[e];
  __syncthreads();
  {
    const int e = wave;   // wave w -> expert w
    f32x4 s = red[0][e][lane];
#pragma unroll
    for (int w = 1; w < 8; w++) s += red[w][e][lane];
#pragma unroll
    for (int rg = 0; rg < 4; rg++) {
      int nn = n0 + quad * 4 + rg;
      float g = gates[nn * 16 + 1 + e];
      Ap[(size_t)nn * KD + Dcfg + e * Rcfg + m] = __float2bfloat16(ALPHA_C * g * s[rg]);
    }
  }
}

// ---------------------------------------------------------------------------
// Launch 3: GEMM  out = A'(N x KD) @ B'(KD x O) + g0[n]*bias[o]
// 256x256 tile, BK=64, 8 waves (2M x 4N, 128x64 per wave), 128 KiB LDS
// double buffer, st_16x32 XOR swizzle, counted-vmcnt 4-phase/K-tile
// schedule (the m201 "8-phase/2-K-tiles" template from the guide).
//
// Swizzle (involution on LDS byte offset): b ^= ((b>>9)&1)<<5.
//   Write side: global_load_lds dest is LINEAR (base + tid*16); the per-lane
//   GLOBAL source is pre-swizzled (rule #21): thread t loads row = u*64+t/8,
//   col = ((t&7)*8) ^ (((t>>5)&1)*16) bf16 elems.
//   Read side: ds_read addr = row*128 + ((kh*64 + quad*16) ^ ((mr&4)<<3)).
//   -> reduces the 16-way stride-128B conflict to ~4-way.
//
// Per K-tile k (buf c = k&1), 4 phases, each {reads; stage; bar; lgkm0;
// setprio1; 16 MFMA; setprio0; bar}:
//   ph1: ds A[i0-3]x2kh (8) + B[j0-1]x2kh (4); stage K_{k+1} B-hi (2 gll)
//   ph2: ds B[j2-3]x2kh (4)
//   ph3: ds A[i4-7]x2kh (8)                       <- all buf-c reads done here
//   ph4: stage K_{k+2} A(4)+B-lo(2) INTO buf c (legal: ph3's closing barrier
//        retired every wave's ds_reads of buf c); reg-only MFMA;
//        s_waitcnt vmcnt(6)  -> K_{k+1}'s 8 issues complete, K_{k+2}'s 6
//        stay in flight (3 half-tiles ahead, per the template); s_barrier.
// Prologue: K0 (8) + K1 (6) issues, vmcnt(6), barrier.
// Tail: kt==64 waits vmcnt(0); kt==65 no stage/wait.
// Accumulation order per element is IDENTICAL to the old 128^2 kernel
// (kt ascending, 32-k chunks ascending) -> bit-identical output.
// ---------------------------------------------------------------------------
#define STG(gbase, lbase, u, ktile)                                              \
  __builtin_amdgcn_global_load_lds(                                              \
      (__attribute__((address_space(1))) void*)((gbase) + (size_t)(u) * 64 * KD  \
                                                + (size_t)(ktile) * 64),         \
      (__attribute__((address_space(3))) void*)((lbase) + (u) * 8192 + dst),     \
      16, 0, 0)

__global__ __launch_bounds__(512, 2) void gemm_kernel(
    const __hip_bfloat16* __restrict__ Ap, const __hip_bfloat16* __restrict__ BT,
    const float* __restrict__ gates, const float* __restrict__ bias,
    float* __restrict__ out) {
  __shared__ char smem[131072];
  const int tid = threadIdx.x;
  const int m0 = blockIdx.y * 256, n0 = blockIdx.x * 256;
  const int wave = tid >> 6, lane = tid & 63;
  const int wm = wave >> 2, wn = wave & 3;       // 2 x 4 wave grid
  const int mr = lane & 15, quad = lane >> 4;

  // staging: per-thread pre-swizzled global source
  const int trow = tid >> 3;                                     // 0..63
  const int cswz = ((tid & 7) << 3) ^ (((tid >> 5) & 1) << 4);   // bf16 elems
  const __hip_bfloat16* gA = Ap + (size_t)(m0 + trow) * KD + cswz;
  const __hip_bfloat16* gB = BT + (size_t)(n0 + trow) * KD + cswz;
  const int dst = tid << 4;

  // swizzled ds_read byte offsets (per-thread constant part)
  const int swz  = (quad << 4) ^ ((mr & 4) << 3);
  const int aoff = (wm * 128 + mr) * 128 + swz;
  const int boff = (wn * 64 + mr) * 128 + swz;

  f32x4 acc[8][4] = {};

  // ---- prologue: K0 all 4 half-tiles (8 issues) + K1 first 3 (6 issues) ----
  STG(gA, smem,          0, 0); STG(gA, smem,          1, 0);
  STG(gA, smem,          2, 0); STG(gA, smem,          3, 0);
  STG(gB, smem + 32768,  0, 0); STG(gB, smem + 32768,  1, 0);
  STG(gB, smem + 32768,  2, 0); STG(gB, smem + 32768,  3, 0);
  STG(gA, smem + 65536,  0, 1); STG(gA, smem + 65536,  1, 1);
  STG(gA, smem + 65536,  2, 1); STG(gA, smem + 65536,  3, 1);
  STG(gB, smem + 98304,  0, 1); STG(gB, smem + 98304,  1, 1);
  asm volatile("s_waitcnt vmcnt(6)" ::: "memory");
  __builtin_amdgcn_s_barrier();

  for (int kt = 0; kt < NKT; ++kt) {
    const bool odd = kt & 1;
    const char* At = odd ? (smem + 65536) : smem;            // compute buf
    const char* Bt = odd ? (smem + 98304) : (smem + 32768);
    char* An = odd ? smem : (smem + 65536);                  // next buf
    char* Bn = odd ? (smem + 32768) : (smem + 98304);

    bf16x8 a[4][2], b0r[2][2], b1r[2][2];

    // ---------------- phase 1 ----------------
#pragma unroll
    for (int i = 0; i < 4; ++i)
#pragma unroll
      for (int kh = 0; kh < 2; ++kh)
        a[i][kh] = *(const bf16x8*)(At + aoff + i * 2048 + kh * 64);
#pragma unroll
    for (int j = 0; j < 2; ++j)
#pragma unroll
      for (int kh = 0; kh < 2; ++kh)
        b0r[j][kh] = *(const bf16x8*)(Bt + boff + j * 2048 + kh * 64);
    if (kt + 1 < NKT) { STG(gB, Bn, 2, kt + 1); STG(gB, Bn, 3, kt + 1); }
    __builtin_amdgcn_s_barrier();
    asm volatile("s_waitcnt lgkmcnt(0)" ::: "memory");
    __builtin_amdgcn_s_setprio(1);
#pragma unroll
    for (int i = 0; i < 4; ++i)
#pragma unroll
      for (int j = 0; j < 2; ++j)
#pragma unroll
        for (int kh = 0; kh < 2; ++kh)
          acc[i][j] = __builtin_amdgcn_mfma_f32_16x16x32_bf16(a[i][kh], b0r[j][kh], acc[i][j], 0, 0, 0);
    __builtin_amdgcn_s_setprio(0);
    __builtin_amdgcn_s_barrier();

    // ---------------- phase 2 ----------------
#pragma unroll
    for (int j = 0; j < 2; ++j)
#pragma unroll
      for (int kh = 0; kh < 2; ++kh)
        b1r[j][kh] = *(const bf16x8*)(Bt + boff + (2 + j) * 2048 + kh * 64);
    __builtin_amdgcn_s_barrier();
    asm volatile("s_waitcnt lgkmcnt(0)" ::: "memory");
    __builtin_amdgcn_s_setprio(1);
#pragma unroll
    for (int i = 0; i < 4; ++i)
#pragma unroll
      for (int j = 0; j < 2; ++j)
#pragma unroll
        for (int kh = 0; kh < 2; ++kh)
          acc[i][2 + j] = __builtin_amdgcn_mfma_f32_16x16x32_bf16(a[i][kh], b1r[j][kh], acc[i][2 + j], 0, 0, 0);
    __builtin_amdgcn_s_setprio(0);
    __builtin_amdgcn_s_barrier();

    // ---------------- phase 3 ----------------
#pragma unroll
    for (int i = 0; i < 4; ++i)
#pragma unroll
      for (int kh = 0; kh < 2; ++kh)
        a[i][kh] = *(const bf16x8*)(At + aoff + (4 + i) * 2048 + kh * 64);
    __builtin_amdgcn_s_barrier();
    asm volatile("s_waitcnt lgkmcnt(0)" ::: "memory");
    __builtin_amdgcn_s_setprio(1);
#pragma unroll
    for (int i = 0; i < 4; ++i)
#pragma unroll
      for (int j = 0; j < 2; ++j)
#pragma unroll
        for (int kh = 0; kh < 2; ++kh)
          acc[4 + i][2 + j] = __builtin_amdgcn_mfma_f32_16x16x32_bf16(a[i][kh], b1r[j][kh], acc[4 + i][2 + j], 0, 0, 0);
    __builtin_amdgcn_s_setprio(0);
    __builtin_amdgcn_s_barrier();

    // ---------------- phase 4 (reg-only MFMA; stage K_{kt+2} into buf c) ----
    if (kt + 2 < NKT) {
      char* Ac = (char*)At; char* Bc = (char*)Bt;
      STG(gA, Ac, 0, kt + 2); STG(gA, Ac, 1, kt + 2);
      STG(gA, Ac, 2, kt + 2); STG(gA, Ac, 3, kt + 2);
      STG(gB, Bc, 0, kt + 2); STG(gB, Bc, 1, kt + 2);
    }
    __builtin_amdgcn_s_setprio(1);
#pragma unroll
    for (int i = 0; i < 4; ++i)
#pragma unroll
      for (int j = 0; j < 2; ++j)
#pragma unroll
        for (int kh = 0; kh < 2; ++kh)
          acc[4 + i][j] = __builtin_amdgcn_mfma_f32_16x16x32_bf16(a[i][kh], b0r[j][kh], acc[4 + i][j], 0, 0, 0);
    __builtin_amdgcn_s_setprio(0);
    if (kt + 2 < NKT) {
      asm volatile("s_waitcnt vmcnt(6)" ::: "memory");
    } else if (kt + 1 < NKT) {
      asm volatile("s_waitcnt vmcnt(0)" ::: "memory");
    }
    if (kt + 1 < NKT) __builtin_amdgcn_s_barrier();
  }

  // ---------------- epilogue ----------------
  float bv[4];
#pragma unroll
  for (int j = 0; j < 4; ++j) bv[j] = bias[n0 + wn * 64 + j * 16 + mr];
#pragma unroll
  for (int i = 0; i < 8; ++i) {
    const int rowb = m0 + wm * 128 + i * 16 + quad * 4;
#pragma unroll
    for (int rg = 0; rg < 4; ++rg) {
      const int row = rowb + rg;
      const float g0 = gates[row * 16];
      float* orow = out + (size_t)row * Ocfg + n0 + wn * 64 + mr;
#pragma unroll
      for (int j = 0; j < 4; ++j)
        orow[j * 16] = acc[i][j][rg] + g0 * bv[j];
    }
  }
}

// ---------------------------------------------------------------------------
extern "C" void kernel_launch(void* const* d_in, const int* in_sizes, int n_in,
                              void* d_out, int out_size, void* d_ws, size_t ws_size,
                              hipStream_t stream) {
  const float* x  = (const float*)d_in[0];
  const float* W  = (const float*)d_in[1];   // (D, O)
  const float* b  = (const float*)d_in[2];   // (O,)
  const float* lA = (const float*)d_in[3];   // (E, D, R)
  const float* lB = (const float*)d_in[4];   // (E, R, O)
  const float* gw = (const float*)d_in[5];   // (E+1, D)
  // d_in[6] = bvv, unused by the reference
  float* out = (float*)d_out;

  char* ws = (char*)d_ws;
  __hip_bfloat16* BT    = (__hip_bfloat16*)(ws + BT_OFF);
  __hip_bfloat16* Ap    = (__hip_bfloat16*)(ws + AP_OFF);
  __hip_bfloat16* AT    = (__hip_bfloat16*)(ws + AT_OFF);
  float*          gates = (float*)(ws + G_OFF);

  prep_parallel_kernel<<<dim3(4864), 256, 0, stream>>>(x, gw, W, lB, lA, gates, Ap, BT, AT);
  lora_t_kernel<<<dim3(Ncfg / 16), 512, 0, stream>>>(x, AT, gates, Ap);
  gemm_kernel<<<dim3(Ocfg / 256, Ncfg / 256), 512, 0, stream>>>(Ap, BT, gates, b, out);
}

// Round 2
// 347.361 us; speedup vs baseline: 1.1541x; 1.0340x over previous
//
#include <hip/hip_runtime.h>
#include <hip/hip_bf16.h>
#include <math.h>

// Problem constants
constexpr int Ncfg = 4096;
constexpr int Dcfg = 4096;
constexpr int Ocfg = 4096;
constexpr int Ecfg = 8;
constexpr int Rcfg = 16;
constexpr int KD   = Dcfg + Ecfg * Rcfg;   // 4224 fused-K
constexpr int NKT  = KD / 64;              // 66 K-tiles of BK=64
constexpr float ALPHA_C = 1.0f;
constexpr double TEMP_C = 1.0;

// Workspace layout (bytes)
constexpr size_t BT_OFF = 0;                                   // B'^T bf16 [O][KD]
constexpr size_t AP_OFF = BT_OFF + (size_t)Ocfg * KD * 2;      // A'   bf16 [N][KD]
constexpr size_t AT_OFF = AP_OFF + (size_t)Ncfg * KD * 2;      // lora_A^T bf16 [E][R][D]
constexpr size_t G_OFF  = AT_OFF + (size_t)Ecfg * Rcfg * Dcfg * 2; // gates f32 [N][16]

typedef short bf16x8 __attribute__((ext_vector_type(8)));
typedef float f32x4  __attribute__((ext_vector_type(4)));

__device__ __forceinline__ void async_load16(const __hip_bfloat16* g, __hip_bfloat16* l) {
  __builtin_amdgcn_global_load_lds((__attribute__((address_space(1))) void*)(g),
                                   (__attribute__((address_space(3))) void*)(l), 16, 0, 0);
}

// ---------------------------------------------------------------------------
// Launch 1: four MUTUALLY INDEPENDENT families in one wide kernel.
//   (unchanged — verified)
// ---------------------------------------------------------------------------
__global__ __launch_bounds__(256) void prep_parallel_kernel(
    const float* __restrict__ x,  const float* __restrict__ gw,
    const float* __restrict__ W,  const float* __restrict__ lB,
    const float* __restrict__ lA,
    float* __restrict__ gates, __hip_bfloat16* __restrict__ Ap,
    __hip_bfloat16* __restrict__ BT, __hip_bfloat16* __restrict__ AT) {
  __shared__ union {
    float tile[64][65];     // 64x64 transpose staging (+1 pad)
    float atile[256][17];   // loraA staging
  } sm;
  const int bid = blockIdx.x;
  const int tid = threadIdx.x;

  if (bid < 512) {
    // ---------------- gates + base-scale ----------------
    const int wave = tid >> 6, lane = tid & 63;
    const int na = bid * 8 + wave * 2, nb = na + 1;   // 2 rows per wave
    const float4* xa4 = (const float4*)(x + (size_t)na * Dcfg);
    const float4* xb4 = (const float4*)(x + (size_t)nb * Dcfg);
    const float4* gw4 = (const float4*)gw;
    double accA[9], accB[9];
#pragma unroll
    for (int e = 0; e < 9; e++) { accA[e] = 0.0; accB[e] = 0.0; }
    for (int i = 0; i < 16; i++) {
      int fi = lane + 64 * i;
      float4 xa = xa4[fi], xb = xb4[fi];
#pragma unroll
      for (int e = 0; e < 9; e++) {
        float4 w = gw4[e * 1024 + fi];   // shared load serves both rows
        accA[e] += (double)xa.x * (double)w.x + (double)xa.y * (double)w.y +
                   (double)xa.z * (double)w.z + (double)xa.w * (double)w.w;
        accB[e] += (double)xb.x * (double)w.x + (double)xb.y * (double)w.y +
                   (double)xb.z * (double)w.z + (double)xb.w * (double)w.w;
      }
    }
#pragma unroll
    for (int off = 32; off >= 1; off >>= 1) {
#pragma unroll
      for (int e = 0; e < 9; e++) {
        accA[e] += __shfl_xor(accA[e], off, 64);
        accB[e] += __shfl_xor(accB[e], off, 64);
      }
    }
    float g0A_l = 0.f, g0B_l = 0.f;
    if (lane == 0) {
#pragma unroll
      for (int r = 0; r < 2; r++) {
        double lg[9];
#pragma unroll
        for (int e = 0; e < 9; e++) lg[e] = r ? accB[e] : accA[e];
        // top-2 over experts 1..8, lowest index wins ties (jax top_k)
        int i1 = 1;
        for (int e = 2; e <= 8; e++) if (lg[e] > lg[i1]) i1 = e;
        int i2 = -1; double v2 = -1e300;
        for (int e = 1; e <= 8; e++) if (e != i1 && lg[e] > v2) { v2 = lg[e]; i2 = e; }
        double vals[9];
        vals[0] = lg[0];
        for (int e = 1; e <= 8; e++) vals[e] = (e == i1 || e == i2) ? lg[e] : 0.0; // zeros, NOT -inf
        double mx = vals[0];
        for (int e = 1; e < 9; e++) mx = fmax(mx, vals[e]);
        double se = 0.0, ex[9];
        for (int e = 0; e < 9; e++) { ex[e] = exp((vals[e] - mx) / TEMP_C); se += ex[e]; }
        const int n = r ? nb : na;
        for (int e = 0; e < 9; e++) gates[n * 16 + e] = (float)(ex[e] / se);
        if (r == 0) g0A_l = (float)(ex[0] / se); else g0B_l = (float)(ex[0] / se);
      }
    }
    const float g0A = __shfl(g0A_l, 0, 64);
    const float g0B = __shfl(g0B_l, 0, 64);
    // Phase B: base-scale writes (x rows are L2-hot from phase A)
    __hip_bfloat16* ara = Ap + (size_t)na * KD;
    __hip_bfloat16* arb = Ap + (size_t)nb * KD;
    for (int i = 0; i < 16; i++) {
      int fi = lane + 64 * i;
      float4 xa = xa4[fi], xb = xb4[fi];
      union { ushort4 u; __hip_bfloat16 h[4]; } p;
      p.h[0] = __float2bfloat16(g0A * xa.x);
      p.h[1] = __float2bfloat16(g0A * xa.y);
      p.h[2] = __float2bfloat16(g0A * xa.z);
      p.h[3] = __float2bfloat16(g0A * xa.w);
      *(ushort4*)(ara + (size_t)fi * 4) = p.u;
      p.h[0] = __float2bfloat16(g0B * xb.x);
      p.h[1] = __float2bfloat16(g0B * xb.y);
      p.h[2] = __float2bfloat16(g0B * xb.z);
      p.h[3] = __float2bfloat16(g0B * xb.w);
      *(ushort4*)(arb + (size_t)fi * 4) = p.u;
    }
  } else if (bid < 4736) {
    // ---------------- W / lora_B transpose+cast, 64x64 tile ----------------
    const float* src; int r0, c0, dstOff;
    if (bid < 4608) {          // W: id in [0,4096)
      int id = bid - 512;
      src = W; r0 = (id & 63) * 64; c0 = (id >> 6) * 64; dstOff = 0;
    } else {                   // lB flat (128 x O): id in [0,128)
      int id = bid - 4608;
      src = lB; r0 = (id & 1) * 64; c0 = (id >> 1) * 64; dstOff = Dcfg;
    }
#pragma unroll
    for (int it = 0; it < 4; it++) {
      int flat = it * 256 + tid;
      int i = flat >> 4, f = flat & 15;
      float4 v = *(const float4*)(src + (size_t)(r0 + i) * Ocfg + c0 + 4 * f);
      sm.tile[i][4 * f + 0] = v.x;
      sm.tile[i][4 * f + 1] = v.y;
      sm.tile[i][4 * f + 2] = v.z;
      sm.tile[i][4 * f + 3] = v.w;
    }
    __syncthreads();
#pragma unroll
    for (int it = 0; it < 4; it++) {
      int flat = it * 256 + tid;
      int j = flat >> 4, q = flat & 15;
      union { ushort4 u; __hip_bfloat16 h[4]; } p;
      p.h[0] = __float2bfloat16(sm.tile[4 * q + 0][j]);
      p.h[1] = __float2bfloat16(sm.tile[4 * q + 1][j]);
      p.h[2] = __float2bfloat16(sm.tile[4 * q + 2][j]);
      p.h[3] = __float2bfloat16(sm.tile[4 * q + 3][j]);
      *(ushort4*)(BT + (size_t)(c0 + j) * KD + dstOff + r0 + 4 * q) = p.u;
    }
  } else {
    // ---------------- lora_A (E,D,R) -> AT (E,R,D) bf16 ----------------
    const int id = bid - 4736;
    const int e = id >> 4, d0 = (id & 15) * 256;
#pragma unroll
    for (int it = 0; it < 16; it++) {
      int idx = it * 256 + tid;
      int d = idx >> 4, rr = idx & 15;
      sm.atile[d][rr] = lA[((size_t)e * Dcfg + d0 + d) * Rcfg + rr];
    }
    __syncthreads();
#pragma unroll
    for (int rr = 0; rr < Rcfg; rr++) {
      AT[((size_t)e * Rcfg + rr) * Dcfg + d0 + tid] = __float2bfloat16(sm.atile[tid][rr]);
    }
  }
}

// ---------------------------------------------------------------------------
// Launch 2: t[n,e,:] = x[n,:] @ lora_A[e] via 16x16x32 bf16 MFMA.
//   (unchanged — verified)
// ---------------------------------------------------------------------------
__global__ __launch_bounds__(512) void lora_t_kernel(
    const float* __restrict__ x, const __hip_bfloat16* __restrict__ AT,
    const float* __restrict__ gates, __hip_bfloat16* __restrict__ Ap) {
  const int n0 = blockIdx.x * 16;
  const int tid = threadIdx.x;
  const int wave = tid >> 6, lane = tid & 63;
  const int m = lane & 15, quad = lane >> 4;
  const int kbase = wave * 512;

  f32x4 acc[8] = {};
  const float* xrow = x + (size_t)(n0 + m) * Dcfg + kbase + quad * 8;
  const __hip_bfloat16* atb = AT + (size_t)m * Dcfg + kbase + quad * 8;
#pragma unroll 2
  for (int kb = 0; kb < 512; kb += 32) {
    float4 x0 = *(const float4*)(xrow + kb);
    float4 x1 = *(const float4*)(xrow + kb + 4);
    union { bf16x8 v; __hip_bfloat16 h[8]; } a;
    a.h[0] = __float2bfloat16(x0.x); a.h[1] = __float2bfloat16(x0.y);
    a.h[2] = __float2bfloat16(x0.z); a.h[3] = __float2bfloat16(x0.w);
    a.h[4] = __float2bfloat16(x1.x); a.h[5] = __float2bfloat16(x1.y);
    a.h[6] = __float2bfloat16(x1.z); a.h[7] = __float2bfloat16(x1.w);
#pragma unroll
    for (int e = 0; e < Ecfg; e++) {
      bf16x8 b = *(const bf16x8*)(atb + (size_t)e * Rcfg * Dcfg + kb);
      acc[e] = __builtin_amdgcn_mfma_f32_16x16x32_bf16(a.v, b, acc[e], 0, 0, 0);
    }
  }
  __shared__ f32x4 red[8][8][64];
#pragma unroll
  for (int e = 0; e < Ecfg; e++) red[wave][e][lane] = acc[e];
  __syncthreads();
  {
    const int e = wave;   // wave w -> expert w
    f32x4 s = red[0][e][lane];
#pragma unroll
    for (int w = 1; w < 8; w++) s += red[w][e][lane];
#pragma unroll
    for (int rg = 0; rg < 4; rg++) {
      int nn = n0 + quad * 4 + rg;
      float g = gates[nn * 16 + 1 + e];
      Ap[(size_t)nn * KD + Dcfg + e * Rcfg + m] = __float2bfloat16(ALPHA_C * g * s[rg]);
    }
  }
}

// ---------------------------------------------------------------------------
// Launch 3: GEMM  out = A'(N x KD) @ B'(KD x O) + g0[n]*bias[o]
// 256x256 tile, BK=64, 8 waves (2M x 4N, 128x64 per wave), 128 KiB LDS
// double buffer, counted-vmcnt 4-phase/K-tile schedule (m201 template).
//
// R2 CHANGE: full 3-bit slot swizzle (was 1-bit -> 8-way conflicts, 1.3e7).
//   LDS rows are 128 B = 8 x 16B slots. Involution: slot ^= (row & 7).
//   Write side (rule #21): global_load_lds dest stays LINEAR (tid*16);
//     per-thread GLOBAL source col slot = (tid&7) ^ ((tid>>3)&7).
//     Wave still reads 8 contiguous 128B segments -> coalescing unchanged.
//   Read side: col byte = (kh*64 + quad*16) ^ ((mr&7)<<4); all row bases
//     (wm*128, wn*64, i*16, j*16) are multiples of 8 so row&7 == mr&7.
//   Result: a quarter-wave's 16 lanes cover all 8 slots, 2 lanes/slot ->
//   2-way aliasing = free (m136). Predicted SQ_LDS_BANK_CONFLICT -> ~0.
//
// Per K-tile k (buf c = k&1), 4 phases, each {reads; stage; bar; lgkm0;
// setprio1; 16 MFMA; setprio0; bar}:
//   ph1: ds A[i0-3]x2kh (8) + B[j0-1]x2kh (4); stage K_{k+1} B-hi (2 gll)
//   ph2: ds B[j2-3]x2kh (4)
//   ph3: ds A[i4-7]x2kh (8)                       <- all buf-c reads done here
//   ph4: stage K_{k+2} A(4)+B-lo(2) INTO buf c; reg-only MFMA;
//        s_waitcnt vmcnt(6); s_barrier.
// Prologue: K0 (8) + K1 (6) issues, vmcnt(6), barrier.
// Tail: kt==64 waits vmcnt(0); kt==65 no stage/wait.
// Accumulation order per element is IDENTICAL to the 128^2 kernel
// (kt ascending, 32-k chunks ascending) -> bit-identical output.
// ---------------------------------------------------------------------------
#define STG(gbase, lbase, u, ktile)                                              \
  __builtin_amdgcn_global_load_lds(                                              \
      (__attribute__((address_space(1))) void*)((gbase) + (size_t)(u) * 64 * KD  \
                                                + (size_t)(ktile) * 64),         \
      (__attribute__((address_space(3))) void*)((lbase) + (u) * 8192 + dst),     \
      16, 0, 0)

__global__ __launch_bounds__(512, 2) void gemm_kernel(
    const __hip_bfloat16* __restrict__ Ap, const __hip_bfloat16* __restrict__ BT,
    const float* __restrict__ gates, const float* __restrict__ bias,
    float* __restrict__ out) {
  __shared__ char smem[131072];
  const int tid = threadIdx.x;
  const int m0 = blockIdx.y * 256, n0 = blockIdx.x * 256;
  const int wave = tid >> 6, lane = tid & 63;
  const int wm = wave >> 2, wn = wave & 3;       // 2 x 4 wave grid
  const int mr = lane & 15, quad = lane >> 4;

  // staging: per-thread pre-swizzled global source (3-bit slot involution)
  const int trow = tid >> 3;                                       // 0..63
  const int cswz = (((tid & 7) ^ ((tid >> 3) & 7)) << 3);          // bf16 elems
  const __hip_bfloat16* gA = Ap + (size_t)(m0 + trow) * KD + cswz;
  const __hip_bfloat16* gB = BT + (size_t)(n0 + trow) * KD + cswz;
  const int dst = tid << 4;

  // swizzled ds_read: col byte = (kh*64 + quad*16) ^ rswz, rswz = (mr&7)<<4
  const int rswz = (mr & 7) << 4;
  const int arow = (wm * 128 + mr) * 128;
  const int brow = (wn * 64 + mr) * 128;

  f32x4 acc[8][4] = {};

  // ---- prologue: K0 all 4 half-tiles (8 issues) + K1 first 3 (6 issues) ----
  STG(gA, smem,          0, 0); STG(gA, smem,          1, 0);
  STG(gA, smem,          2, 0); STG(gA, smem,          3, 0);
  STG(gB, smem + 32768,  0, 0); STG(gB, smem + 32768,  1, 0);
  STG(gB, smem + 32768,  2, 0); STG(gB, smem + 32768,  3, 0);
  STG(gA, smem + 65536,  0, 1); STG(gA, smem + 65536,  1, 1);
  STG(gA, smem + 65536,  2, 1); STG(gA, smem + 65536,  3, 1);
  STG(gB, smem + 98304,  0, 1); STG(gB, smem + 98304,  1, 1);
  asm volatile("s_waitcnt vmcnt(6)" ::: "memory");
  __builtin_amdgcn_s_barrier();

  for (int kt = 0; kt < NKT; ++kt) {
    const bool odd = kt & 1;
    const char* At = odd ? (smem + 65536) : smem;            // compute buf
    const char* Bt = odd ? (smem + 98304) : (smem + 32768);
    char* An = odd ? smem : (smem + 65536);                  // next buf
    char* Bn = odd ? (smem + 32768) : (smem + 98304);

    bf16x8 a[4][2], b0r[2][2], b1r[2][2];

    // ---------------- phase 1 ----------------
#pragma unroll
    for (int i = 0; i < 4; ++i)
#pragma unroll
      for (int kh = 0; kh < 2; ++kh)
        a[i][kh] = *(const bf16x8*)(At + arow + i * 2048 + ((kh * 64 + quad * 16) ^ rswz));
#pragma unroll
    for (int j = 0; j < 2; ++j)
#pragma unroll
      for (int kh = 0; kh < 2; ++kh)
        b0r[j][kh] = *(const bf16x8*)(Bt + brow + j * 2048 + ((kh * 64 + quad * 16) ^ rswz));
    if (kt + 1 < NKT) { STG(gB, Bn, 2, kt + 1); STG(gB, Bn, 3, kt + 1); }
    __builtin_amdgcn_s_barrier();
    asm volatile("s_waitcnt lgkmcnt(0)" ::: "memory");
    __builtin_amdgcn_s_setprio(1);
#pragma unroll
    for (int i = 0; i < 4; ++i)
#pragma unroll
      for (int j = 0; j < 2; ++j)
#pragma unroll
        for (int kh = 0; kh < 2; ++kh)
          acc[i][j] = __builtin_amdgcn_mfma_f32_16x16x32_bf16(a[i][kh], b0r[j][kh], acc[i][j], 0, 0, 0);
    __builtin_amdgcn_s_setprio(0);
    __builtin_amdgcn_s_barrier();

    // ---------------- phase 2 ----------------
#pragma unroll
    for (int j = 0; j < 2; ++j)
#pragma unroll
      for (int kh = 0; kh < 2; ++kh)
        b1r[j][kh] = *(const bf16x8*)(Bt + brow + (2 + j) * 2048 + ((kh * 64 + quad * 16) ^ rswz));
    __builtin_amdgcn_s_barrier();
    asm volatile("s_waitcnt lgkmcnt(0)" ::: "memory");
    __builtin_amdgcn_s_setprio(1);
#pragma unroll
    for (int i = 0; i < 4; ++i)
#pragma unroll
      for (int j = 0; j < 2; ++j)
#pragma unroll
        for (int kh = 0; kh < 2; ++kh)
          acc[i][2 + j] = __builtin_amdgcn_mfma_f32_16x16x32_bf16(a[i][kh], b1r[j][kh], acc[i][2 + j], 0, 0, 0);
    __builtin_amdgcn_s_setprio(0);
    __builtin_amdgcn_s_barrier();

    // ---------------- phase 3 ----------------
#pragma unroll
    for (int i = 0; i < 4; ++i)
#pragma unroll
      for (int kh = 0; kh < 2; ++kh)
        a[i][kh] = *(const bf16x8*)(At + arow + (4 + i) * 2048 + ((kh * 64 + quad * 16) ^ rswz));
    __builtin_amdgcn_s_barrier();
    asm volatile("s_waitcnt lgkmcnt(0)" ::: "memory");
    __builtin_amdgcn_s_setprio(1);
#pragma unroll
    for (int i = 0; i < 4; ++i)
#pragma unroll
      for (int j = 0; j < 2; ++j)
#pragma unroll
        for (int kh = 0; kh < 2; ++kh)
          acc[4 + i][2 + j] = __builtin_amdgcn_mfma_f32_16x16x32_bf16(a[i][kh], b1r[j][kh], acc[4 + i][2 + j], 0, 0, 0);
    __builtin_amdgcn_s_setprio(0);
    __builtin_amdgcn_s_barrier();

    // ---------------- phase 4 (reg-only MFMA; stage K_{kt+2} into buf c) ----
    if (kt + 2 < NKT) {
      char* Ac = (char*)At; char* Bc = (char*)Bt;
      STG(gA, Ac, 0, kt + 2); STG(gA, Ac, 1, kt + 2);
      STG(gA, Ac, 2, kt + 2); STG(gA, Ac, 3, kt + 2);
      STG(gB, Bc, 0, kt + 2); STG(gB, Bc, 1, kt + 2);
    }
    __builtin_amdgcn_s_setprio(1);
#pragma unroll
    for (int i = 0; i < 4; ++i)
#pragma unroll
      for (int j = 0; j < 2; ++j)
#pragma unroll
        for (int kh = 0; kh < 2; ++kh)
          acc[4 + i][j] = __builtin_amdgcn_mfma_f32_16x16x32_bf16(a[i][kh], b0r[j][kh], acc[4 + i][j], 0, 0, 0);
    __builtin_amdgcn_s_setprio(0);
    if (kt + 2 < NKT) {
      asm volatile("s_waitcnt vmcnt(6)" ::: "memory");
    } else if (kt + 1 < NKT) {
      asm volatile("s_waitcnt vmcnt(0)" ::: "memory");
    }
    if (kt + 1 < NKT) __builtin_amdgcn_s_barrier();
  }

  // ---------------- epilogue ----------------
  float bv[4];
#pragma unroll
  for (int j = 0; j < 4; ++j) bv[j] = bias[n0 + wn * 64 + j * 16 + mr];
#pragma unroll
  for (int i = 0; i < 8; ++i) {
    const int rowb = m0 + wm * 128 + i * 16 + quad * 4;
#pragma unroll
    for (int rg = 0; rg < 4; ++rg) {
      const int row = rowb + rg;
      const float g0 = gates[row * 16];
      float* orow = out + (size_t)row * Ocfg + n0 + wn * 64 + mr;
#pragma unroll
      for (int j = 0; j < 4; ++j)
        orow[j * 16] = acc[i][j][rg] + g0 * bv[j];
    }
  }
}

// ---------------------------------------------------------------------------
extern "C" void kernel_launch(void* const* d_in, const int* in_sizes, int n_in,
                              void* d_out, int out_size, void* d_ws, size_t ws_size,
                              hipStream_t stream) {
  const float* x  = (const float*)d_in[0];
  const float* W  = (const float*)d_in[1];   // (D, O)
  const float* b  = (const float*)d_in[2];   // (O,)
  const float* lA = (const float*)d_in[3];   // (E, D, R)
  const float* lB = (const float*)d_in[4];   // (E, R, O)
  const float* gw = (const float*)d_in[5];   // (E+1, D)
  // d_in[6] = bvv, unused by the reference
  float* out = (float*)d_out;

  char* ws = (char*)d_ws;
  __hip_bfloat16* BT    = (__hip_bfloat16*)(ws + BT_OFF);
  __hip_bfloat16* Ap    = (__hip_bfloat16*)(ws + AP_OFF);
  __hip_bfloat16* AT    = (__hip_bfloat16*)(ws + AT_OFF);
  float*          gates = (float*)(ws + G_OFF);

  prep_parallel_kernel<<<dim3(4864), 256, 0, stream>>>(x, gw, W, lB, lA, gates, Ap, BT, AT);
  lora_t_kernel<<<dim3(Ncfg / 16), 512, 0, stream>>>(x, AT, gates, Ap);
  gemm_kernel<<<dim3(Ocfg / 256, Ncfg / 256), 512, 0, stream>>>(Ap, BT, gates, b, out);
}